// Round 10
// baseline (368.141 us; speedup 1.0000x reference)
//
#include <hip/hip_runtime.h>

// FK_Velocity_Loss: pos_loss = vel_loss = mean((out_fk - gt_fk)^2)
// (gt_prev_pose cancels exactly: (o - p) - (g - p) = o - g)
//
// R10 = R4 EXACTLY (3125 blocks x ITERS=4 — oversubscribed grid, 8 waves/SIMD
// resident, the proven 75.7us config; R9 showed TLP is the BW lever) with ONE
// change: finalize fused via last-block-done ticket (no second dispatch).
// NO launch_bounds min-wave cap (R6 lesson: VGPR cap -> scratch spill).

#define N_CHAINS 800000                  // 400000 rows x 2 chains
#define ITERS 4
#define BLOCK 256
#define BLOCKS (N_CHAINS * 4 / ITERS / BLOCK)   // 3125, exact
#define CHAIN_STRIDE (N_CHAINS / ITERS)         // 200000
#define MEAN_DIV (400000.0 * 2.0 * 3.0)

// Broadcast lane (quad_base + I) across the quad. DPP quad_perm, VALU-only.
template <int I>
__device__ __forceinline__ float qb(float x) {
    return __builtin_bit_cast(float,
        __builtin_amdgcn_mov_dpp(__builtin_bit_cast(int, x),
                                 I | (I << 2) | (I << 4) | (I << 6),
                                 0xF, 0xF, true));
}

// Lane holds row k of M0..M3. Returns component k of (M0*M1*M2*M3)[:,3],
// computed right-to-left: v = M3[:,3]; v = M2*v; v = M1*v; v = M0*v.
__device__ __forceinline__ float fk_elem(float4 m0, float4 m1, float4 m2, float4 m3) {
    float v = m3.w;
    float v0, v1, v2, v3;
    v0 = qb<0>(v); v1 = qb<1>(v); v2 = qb<2>(v); v3 = qb<3>(v);
    v = m2.x * v0 + m2.y * v1 + m2.z * v2 + m2.w * v3;
    v0 = qb<0>(v); v1 = qb<1>(v); v2 = qb<2>(v); v3 = qb<3>(v);
    v = m1.x * v0 + m1.y * v1 + m1.z * v2 + m1.w * v3;
    v0 = qb<0>(v); v1 = qb<1>(v); v2 = qb<2>(v); v3 = qb<3>(v);
    v = m0.x * v0 + m0.y * v1 + m0.z * v2 + m0.w * v3;
    return v;
}

__global__ __launch_bounds__(BLOCK) void fk_loss_kernel(const float4* __restrict__ o4,
                                                        const float4* __restrict__ g4,
                                                        unsigned* __restrict__ counter,
                                                        float* __restrict__ partial,
                                                        float* __restrict__ out) {
    const int tid = blockIdx.x * BLOCK + threadIdx.x;
    const int k = tid & 3;          // row within quad
    const int q = tid >> 2;         // base chain index (0..199999)

    const float4* po = o4 + (size_t)q * 16 + k;
    const float4* pg = g4 + (size_t)q * 16 + k;
    float4 o0 = po[0], o1 = po[4], o2 = po[8], o3 = po[12];
    float4 g0 = pg[0], g1 = pg[4], g2 = pg[8], g3 = pg[12];

    float ss = 0.0f;
#pragma unroll
    for (int it = 0; it < ITERS; ++it) {
        float4 no0, no1, no2, no3, ng0, ng1, ng2, ng3;
        if (it + 1 < ITERS) {       // issue next iter's loads BEFORE compute
            const size_t off = ((size_t)q + (size_t)(it + 1) * CHAIN_STRIDE) * 16 + k;
            const float4* qo = o4 + off;
            const float4* qg = g4 + off;
            no0 = qo[0]; no1 = qo[4]; no2 = qo[8]; no3 = qo[12];
            ng0 = qg[0]; ng1 = qg[4]; ng2 = qg[8]; ng3 = qg[12];
        }
        float fo = fk_elem(o0, o1, o2, o3);
        float fg = fk_elem(g0, g1, g2, g3);
        float d = fo - fg;
        ss += (k < 3) ? d * d : 0.0f;
        o0 = no0; o1 = no1; o2 = no2; o3 = no3;
        g0 = ng0; g1 = ng1; g2 = ng2; g3 = ng3;
    }

    // wave64 shuffle reduce, then block reduce, partial store + ticket
#pragma unroll
    for (int off = 32; off > 0; off >>= 1) ss += __shfl_down(ss, off, 64);
    __shared__ float part[BLOCK / 64];
    __shared__ bool amlast;
    if ((threadIdx.x & 63) == 0) part[threadIdx.x >> 6] = ss;
    __syncthreads();
    if (threadIdx.x == 0) {
        float b = part[0] + part[1] + part[2] + part[3];
        __hip_atomic_store(&partial[blockIdx.x], b, __ATOMIC_RELEASE,
                           __HIP_MEMORY_SCOPE_AGENT);
        unsigned prev = __hip_atomic_fetch_add(counter, 1u, __ATOMIC_ACQ_REL,
                                               __HIP_MEMORY_SCOPE_AGENT);
        amlast = (prev == BLOCKS - 1);
    }
    __syncthreads();

    if (amlast) {  // exactly one block, after all partials are visible
        double s = 0.0;
        for (int i = threadIdx.x; i < BLOCKS; i += BLOCK)
            s += (double)__hip_atomic_load(&partial[i], __ATOMIC_ACQUIRE,
                                           __HIP_MEMORY_SCOPE_AGENT);
        __shared__ double dpart[BLOCK / 64];
#pragma unroll
        for (int off = 32; off > 0; off >>= 1) s += __shfl_down(s, off, 64);
        if ((threadIdx.x & 63) == 0) dpart[threadIdx.x >> 6] = s;
        __syncthreads();
        if (threadIdx.x == 0) {
            double b = dpart[0] + dpart[1] + dpart[2] + dpart[3];
            float v = (float)(b / MEAN_DIV);
            out[0] = v;  // pos_loss
            out[1] = v;  // vel_loss (identical: gt_prev cancels)
        }
    }
}

extern "C" void kernel_launch(void* const* d_in, const int* in_sizes, int n_in,
                              void* d_out, int out_size, void* d_ws, size_t ws_size,
                              hipStream_t stream) {
    const float4* output_pose = (const float4*)d_in[0];
    const float4* gt_pose     = (const float4*)d_in[1];
    // d_in[2] (gt_prev_pose) and d_in[3] (gt_pos) are not needed.
    float* out = (float*)d_out;
    unsigned* counter = (unsigned*)d_ws;              // 4 B, zeroed below
    float* partial = (float*)((char*)d_ws + 512);     // BLOCKS floats

    hipMemsetAsync(counter, 0, sizeof(unsigned), stream);   // capturable
    fk_loss_kernel<<<BLOCKS, BLOCK, 0, stream>>>(output_pose, gt_pose,
                                                 counter, partial, out);
}

// Round 11
// 76.287 us; speedup vs baseline: 4.8258x; 4.8258x over previous
//
#include <hip/hip_runtime.h>

// FK_Velocity_Loss: pos_loss = vel_loss = mean((out_fk - gt_fk)^2)
// (gt_prev_pose cancels exactly: (o - p) - (g - p) = o - g)
//
// R11 = R4 byte-for-byte (best: 75.7us). 4 lanes/chain, DPP quad-broadcast
// mat-vec (VALU-only), 1-deep register prefetch, 3125x256 oversubscribed grid
// (8 waves/SIMD — TLP is the BW lever, per R9), plain partial stores +
// separate 1-block finalize (ticket/atomic variants all regressed: R6/R9/R10
// showed agent-scope release/acquire per block serializes L2 maintenance).

#define N_CHAINS 800000                  // 400000 rows x 2 chains
#define ITERS 4
#define BLOCK 256
#define BLOCKS (N_CHAINS * 4 / ITERS / BLOCK)   // 3125, exact
#define CHAIN_STRIDE (N_CHAINS / ITERS)         // 200000
#define MEAN_DIV (400000.0 * 2.0 * 3.0)

// Broadcast lane (quad_base + I) across the quad. DPP quad_perm, 1-cycle VALU.
template <int I>
__device__ __forceinline__ float qb(float x) {
    return __builtin_bit_cast(float,
        __builtin_amdgcn_mov_dpp(__builtin_bit_cast(int, x),
                                 I | (I << 2) | (I << 4) | (I << 6),
                                 0xF, 0xF, true));
}

// Lane holds row k of M0..M3. Returns component k of (M0*M1*M2*M3)[:,3],
// computed right-to-left: v = M3[:,3]; v = M2*v; v = M1*v; v = M0*v.
__device__ __forceinline__ float fk_elem(float4 m0, float4 m1, float4 m2, float4 m3) {
    float v = m3.w;
    float v0, v1, v2, v3;
    v0 = qb<0>(v); v1 = qb<1>(v); v2 = qb<2>(v); v3 = qb<3>(v);
    v = m2.x * v0 + m2.y * v1 + m2.z * v2 + m2.w * v3;
    v0 = qb<0>(v); v1 = qb<1>(v); v2 = qb<2>(v); v3 = qb<3>(v);
    v = m1.x * v0 + m1.y * v1 + m1.z * v2 + m1.w * v3;
    v0 = qb<0>(v); v1 = qb<1>(v); v2 = qb<2>(v); v3 = qb<3>(v);
    v = m0.x * v0 + m0.y * v1 + m0.z * v2 + m0.w * v3;
    return v;
}

__global__ __launch_bounds__(BLOCK) void fk_loss_kernel(const float4* __restrict__ o4,
                                                        const float4* __restrict__ g4,
                                                        float* __restrict__ partial) {
    const int tid = blockIdx.x * BLOCK + threadIdx.x;
    const int k = tid & 3;          // row within quad
    const int q = tid >> 2;         // base chain index

    const float4* po = o4 + (size_t)q * 16 + k;
    const float4* pg = g4 + (size_t)q * 16 + k;
    float4 o0 = po[0], o1 = po[4], o2 = po[8], o3 = po[12];
    float4 g0 = pg[0], g1 = pg[4], g2 = pg[8], g3 = pg[12];

    float ss = 0.0f;
#pragma unroll
    for (int it = 0; it < ITERS; ++it) {
        float4 no0, no1, no2, no3, ng0, ng1, ng2, ng3;
        if (it + 1 < ITERS) {       // issue next iter's loads BEFORE compute
            const size_t off = ((size_t)q + (size_t)(it + 1) * CHAIN_STRIDE) * 16 + k;
            const float4* qo = o4 + off;
            const float4* qg = g4 + off;
            no0 = qo[0]; no1 = qo[4]; no2 = qo[8]; no3 = qo[12];
            ng0 = qg[0]; ng1 = qg[4]; ng2 = qg[8]; ng3 = qg[12];
        }
        float fo = fk_elem(o0, o1, o2, o3);
        float fg = fk_elem(g0, g1, g2, g3);
        float d = fo - fg;
        ss += (k < 3) ? d * d : 0.0f;
        o0 = no0; o1 = no1; o2 = no2; o3 = no3;
        g0 = ng0; g1 = ng1; g2 = ng2; g3 = ng3;
    }

    // wave64 shuffle reduce, then block reduce, one store per block
#pragma unroll
    for (int off = 32; off > 0; off >>= 1) ss += __shfl_down(ss, off, 64);
    __shared__ float part[BLOCK / 64];
    if ((threadIdx.x & 63) == 0) part[threadIdx.x >> 6] = ss;
    __syncthreads();
    if (threadIdx.x == 0)
        partial[blockIdx.x] = part[0] + part[1] + part[2] + part[3];
}

__global__ __launch_bounds__(BLOCK) void fk_finalize(const float* __restrict__ partial,
                                                     float* __restrict__ out) {
    double s = 0.0;
    for (int i = threadIdx.x; i < BLOCKS; i += BLOCK) s += (double)partial[i];
    __shared__ double dpart[BLOCK / 64];
#pragma unroll
    for (int off = 32; off > 0; off >>= 1) s += __shfl_down(s, off, 64);
    if ((threadIdx.x & 63) == 0) dpart[threadIdx.x >> 6] = s;
    __syncthreads();
    if (threadIdx.x == 0) {
        double b = dpart[0] + dpart[1] + dpart[2] + dpart[3];
        float v = (float)(b / MEAN_DIV);
        out[0] = v;  // pos_loss
        out[1] = v;  // vel_loss (identical: gt_prev cancels)
    }
}

extern "C" void kernel_launch(void* const* d_in, const int* in_sizes, int n_in,
                              void* d_out, int out_size, void* d_ws, size_t ws_size,
                              hipStream_t stream) {
    const float4* output_pose = (const float4*)d_in[0];
    const float4* gt_pose     = (const float4*)d_in[1];
    // d_in[2] (gt_prev_pose) and d_in[3] (gt_pos) are not needed.
    float* out = (float*)d_out;
    float* partial = (float*)d_ws;   // BLOCKS floats, fully overwritten each call

    fk_loss_kernel<<<BLOCKS, BLOCK, 0, stream>>>(output_pose, gt_pose, partial);
    fk_finalize<<<1, BLOCK, 0, stream>>>(partial, out);
}